// Round 4
// baseline (374.054 us; speedup 1.0000x reference)
//
#include <hip/hip_runtime.h>
#include <math.h>

#define B_TOT 3072
#define PIX   12288   // 64*64*3 elements per batch image
#define BM    4       // batches per block in kernel A

typedef float v2f __attribute__((ext_vector_type(2)));

// ---------------------------------------------------------------------------
// Kernel A (v3, unchanged control): BM=4, grid 768, 3 blocks/CU x 4 waves.
// fp32 partials + wave shuffles; fp64 cross-wave combine + 2x2 inversion.
// ---------------------------------------------------------------------------
__global__ __launch_bounds__(256) void compute_M_kernel(
    const float* __restrict__ x, const float* __restrict__ w1,
    const float* __restrict__ b1, const float* __restrict__ w2,
    const float* __restrict__ b2, float* __restrict__ Mout) {
  const int b0 = blockIdx.x * BM;
  const float4* __restrict__ w14 = (const float4*)w1;
  const float4* __restrict__ w24 = (const float4*)w2;
  const float4* __restrict__ xb4 = (const float4*)(x + (size_t)b0 * PIX);

  float acc[BM][6];
  #pragma unroll
  for (int b = 0; b < BM; ++b)
    #pragma unroll
    for (int f = 0; f < 6; ++f) acc[b][f] = 0.f;

  #pragma unroll 2
  for (int it = 0; it < PIX / 4 / 256; ++it) {
    const int i4 = threadIdx.x + it * 256;
    float4 a0 = w14[i4 * 3 + 0], a1 = w14[i4 * 3 + 1], a2 = w14[i4 * 3 + 2];
    float4 c0 = w24[i4 * 3 + 0], c1 = w24[i4 * 3 + 1], c2 = w24[i4 * 3 + 2];
    #pragma unroll
    for (int b = 0; b < BM; ++b) {
      float4 xv = xb4[(size_t)b * (PIX / 4) + i4];
      acc[b][0] += xv.x * a0.x + xv.y * a0.w + xv.z * a1.z + xv.w * a2.y;
      acc[b][1] += xv.x * a0.y + xv.y * a1.x + xv.z * a1.w + xv.w * a2.z;
      acc[b][2] += xv.x * a0.z + xv.y * a1.y + xv.z * a2.x + xv.w * a2.w;
      acc[b][3] += xv.x * c0.x + xv.y * c0.w + xv.z * c1.z + xv.w * c2.y;
      acc[b][4] += xv.x * c0.y + xv.y * c1.x + xv.z * c1.w + xv.w * c2.z;
      acc[b][5] += xv.x * c0.z + xv.y * c1.y + xv.z * c2.x + xv.w * c2.w;
    }
  }

  #pragma unroll
  for (int b = 0; b < BM; ++b)
    #pragma unroll
    for (int f = 0; f < 6; ++f)
      #pragma unroll
      for (int off = 32; off > 0; off >>= 1)
        acc[b][f] += __shfl_down(acc[b][f], off, 64);

  __shared__ float wred[4][BM][6];
  const int wave = threadIdx.x >> 6, lane = threadIdx.x & 63;
  if (lane == 0) {
    #pragma unroll
    for (int b = 0; b < BM; ++b)
      #pragma unroll
      for (int f = 0; f < 6; ++f) wred[wave][b][f] = acc[b][f];
  }
  __syncthreads();

  if (threadIdx.x < BM) {
    const int b = threadIdx.x;
    double v[3][2];
    for (int c = 0; c < 3; ++c) {
      v[c][0] = (double)wred[0][b][c] + (double)wred[1][b][c] +
                (double)wred[2][b][c] + (double)wred[3][b][c] + (double)b1[c];
      v[c][1] = (double)wred[0][b][3 + c] + (double)wred[1][b][3 + c] +
                (double)wred[2][b][3 + c] + (double)wred[3][b][3 + c] +
                (double)b2[c];
    }
    for (int k = 0; k < 2; ++k) {
      double l1 = 1e-6 + fabs(v[0][k]) + fabs(v[1][k]) + fabs(v[2][k]);
      for (int c = 0; c < 3; ++c) v[c][k] /= l1;
    }
    double G00 = 0, G01 = 0, G11 = 0;
    for (int c = 0; c < 3; ++c) {
      G00 += v[c][0] * v[c][0];
      G01 += v[c][0] * v[c][1];
      G11 += v[c][1] * v[c][1];
    }
    double det = G00 * G11 - G01 * G01;
    double i00 = G11 / det, i01 = -G01 / det, i11 = G00 / det;
    float* Mo = Mout + (size_t)(b0 + b) * 6;
    for (int c = 0; c < 3; ++c) {
      Mo[0 * 3 + c] = (float)(i00 * v[c][0] + i01 * v[c][1]);
      Mo[1 * 3 + c] = (float)(i01 * v[c][0] + i11 * v[c][1]);
    }
  }
}

// ---------------------------------------------------------------------------
// Kernel B (v4): one block per output image b2 (2048 blocks).
//   R3 post-mortem: old phase 1 loaded per-thread 48B pixel groups at 48B
//   lane stride -> ~48 line-transactions per dwordx4 (3x amplification),
//   ~864 lines/wave-image = ~11.5 us of L1-issue per CU (serial resource).
//   New structure:
//   Phase 1: stage RAW x linearly into LDS. Block's z-range [zbase,+12288)
//   maps to x floats [3*(zbase>>1), +18432) -- contiguous 73728 B (global
//   x float index = 3*(m>>1)). Thread t copies float4 {t, t+256, ..,
//   t+17*256}: fully coalesced (16 lines/instr, 288 lines/wave-image).
//   Loads all issue before LDS writes (18-deep vmcnt pipeline).
//   Phase 2: the M.x multiply moves here. Lane owns col = wave*48+lane
//   (identical col<->(w,c) map as before: col = w*3+c, w=wave*16+lane/3).
//   k = col&1 (zbase always even), pixel-col q = col>>1; per h the 3 x
//   floats sit at xl[288h+3q]: lane pairs (k=0/1) broadcast, 24 distinct
//   pixels at stride-3 dwords are conflict-free (3 coprime to 32).
//   Batch boundary inside a column: b = b_lo+1 iff h >= h_sw where
//   h_sw = ceil((8192 - 4096*(b2&1) - col)/192)  (4096*(b2&1) = zbase&8191;
//   m&8191 crosses 8192 at most once since max < 16384). Per-h row select
//   via 3 cndmasks. Hilbert taps + wave-internal 3-lane transpose + 384B
//   contiguous nontemporal stores unchanged (verified path).
// ---------------------------------------------------------------------------
__global__ __launch_bounds__(256) void z_hilbert_kernel(
    const float* __restrict__ x, const float* __restrict__ M,
    float* __restrict__ out) {
  const int b2 = blockIdx.x;
  __shared__ __align__(16) float xl[18432];   // 72 KB raw x slab
  __shared__ float Ms[12];
  const size_t zbase = (size_t)b2 * PIX;
  const int b_lo = (int)(zbase >> 13);

  // Phase 1: coalesced linear copy of the 73728-B x slab into LDS.
  {
    const float4* xs4 = (const float4*)(x + (size_t)(zbase >> 1) * 3);
    float4* xl4 = (float4*)xl;
    float4 t[18];
    #pragma unroll
    for (int j = 0; j < 18; ++j) t[j] = xs4[threadIdx.x + j * 256];
    if (threadIdx.x < 12) {   // overlap M fetch with x loads in flight
      int bb = b_lo + (int)(threadIdx.x / 6);
      float mv = 0.f;
      if (bb < B_TOT) mv = M[(size_t)bb * 6 + (threadIdx.x % 6)];
      Ms[threadIdx.x] = mv;
    }
    #pragma unroll
    for (int j = 0; j < 18; ++j) xl4[threadIdx.x + j * 256] = t[j];
  }
  __syncthreads();

  float* outb = out + (size_t)b2 * 24576;   // (64,64,6) per image

  // Phase 2
  const int wave = threadIdx.x >> 6, lane = threadIdx.x & 63;
  if (lane < 48) {
    const int w = wave * 16 + lane / 3;
    const int c = lane % 3;
    const int col = w * 3 + c;          // == wave*48 + lane
    const int k = col & 1;
    const int q = col >> 1;             // pixel-column 0..95
    const float mlo0 = Ms[k * 3 + 0], mlo1 = Ms[k * 3 + 1], mlo2 = Ms[k * 3 + 2];
    const float mhi0 = Ms[6 + k * 3 + 0], mhi1 = Ms[6 + k * 3 + 1],
                mhi2 = Ms[6 + k * 3 + 2];
    const int r_th = 8192 - ((b2 & 1) << 12) - col;   // always > 0
    const int h_sw = (r_th + 191) / 192;              // h >= h_sw -> b_lo+1

    float gc[16];
    #pragma unroll
    for (int jj = 0; jj < 16; ++jj) {
      float ang = 3.14159265358979323846f * (float)(2 * jj + 1) / 64.0f;
      gc[jj] = 0.03125f * cosf(ang) / sinf(ang);   // (1/32)cot(pi d/64), odd d
    }

    float v[64];
    const float* xq = xl + 3 * q;
    #pragma unroll
    for (int h = 0; h < 64; ++h) {
      float x0 = xq[288 * h + 0];
      float x1 = xq[288 * h + 1];
      float x2 = xq[288 * h + 2];
      bool hi = (h >= h_sw);
      float m0 = hi ? mhi0 : mlo0;
      float m1 = hi ? mhi1 : mlo1;
      float m2 = hi ? mhi2 : mlo2;
      v[h] = m0 * x0 + m1 * x1 + m2 * x2;
    }

    float* oc = outb + w * 6 + c * 2;   // this lane's float2 slot per pixel
    #pragma unroll
    for (int h = 0; h < 64; ++h) {
      float acc = 0.f;
      #pragma unroll
      for (int jj = 0; jj < 16; ++jj) {
        int d = 2 * jj + 1;
        acc += gc[jj] * (v[(h - d) & 63] - v[(h + d) & 63]);
      }
      float r = v[h];
      // lane transpose within group of 3: pixel = [r0,r1,r2,a0,a1,a2]
      float s1 = __shfl(r, lane + 1, 64);    // r of next lane (c+1)
      float s2 = __shfl(acc, lane - 1, 64);  // a of prev lane (c-1)
      v2f st;
      st.x = (c == 0) ? r : ((c == 1) ? s1 : s2);
      st.y = (c == 0) ? s1 : ((c == 1) ? s2 : acc);
      __builtin_nontemporal_store(st, (v2f*)(oc + (size_t)h * 384));
    }
  }
}

extern "C" void kernel_launch(void* const* d_in, const int* in_sizes, int n_in,
                              void* d_out, int out_size, void* d_ws, size_t ws_size,
                              hipStream_t stream) {
  const float* x  = (const float*)d_in[0];   // (3072,64,64,3)
  const float* w1 = (const float*)d_in[1];   // (64,64,3,3)
  const float* b1 = (const float*)d_in[2];   // (3,)
  const float* w2 = (const float*)d_in[3];   // (64,64,3,3)
  const float* b2 = (const float*)d_in[4];   // (3,)
  float* out = (float*)d_out;                // (2048,64,64,6)
  float* M = (float*)d_ws;                   // 3072*6 floats

  compute_M_kernel<<<B_TOT / BM, 256, 0, stream>>>(x, w1, b1, w2, b2, M);
  z_hilbert_kernel<<<2048, 256, 0, stream>>>(x, M, out);
}